// Round 1
// baseline (4373.339 us; speedup 1.0000x reference)
//
#include <hip/hip_runtime.h>

#define TT 4096
#define HDIM 64
#define DPROJ 800000

__device__ __forceinline__ float fexp2(float x) { return __builtin_amdgcn_exp2f(x); }
__device__ __forceinline__ float frcp(float x) { return __builtin_amdgcn_rcpf(x); }
// sigmoid(x) = 1/(1+e^-x)
__device__ __forceinline__ float sigm(float x) { return frcp(1.0f + fexp2(-1.44269504f * x)); }
// tanh(x) = 1 - 2/(e^{2x}+1)
__device__ __forceinline__ float tanh_(float x) { return 1.0f - 2.0f * frcp(1.0f + fexp2(2.88539008f * x)); }

// Kernel 1: gx0[t][j] = dot(x[t,:], w_ih0[j,:]) + b_ih0[j] + b_hh0[j]
__global__ __launch_bounds__(256) void gx0_kernel(const float* __restrict__ x,
                                                  const float* __restrict__ w_ih0,
                                                  const float* __restrict__ b_ih0,
                                                  const float* __restrict__ b_hh0,
                                                  float* __restrict__ gx0) {
    __shared__ float xs[32];
    const int t = blockIdx.x;
    const int j = threadIdx.x;
    if (j < 32) xs[j] = x[t * 32 + j];
    __syncthreads();
    const float4* w4 = (const float4*)(w_ih0 + j * 32);
    const float4* x4 = (const float4*)xs;
    float acc = b_ih0[j] + b_hh0[j];
#pragma unroll
    for (int u = 0; u < 8; ++u) {
        float4 w = w4[u];
        float4 xv = x4[u];
        acc += w.x * xv.x + w.y * xv.y + w.z * xv.z + w.w * xv.w;
    }
    gx0[t * 256 + j] = acc;
}

// Kernel 2: the sequential 2-layer LSTM, one workgroup, layers pipelined.
// Threads 0..255  (group A): layer0 gate row j   (w_hh0 row in VGPRs)
// Threads 256..511 (group B): layer1 gate row j  (w_ih1 + w_hh1 rows in VGPRs)
// Super-step s: A computes layer0 time s, B computes layer1 time s-1.
__global__ __launch_bounds__(512, 2) void lstm_kernel(const float* __restrict__ gx0,
                                                      const float* __restrict__ w_hh0,
                                                      const float* __restrict__ w_ih1,
                                                      const float* __restrict__ w_hh1,
                                                      const float* __restrict__ b_ih1,
                                                      const float* __restrict__ b_hh1,
                                                      float* __restrict__ hc_out) {
    __shared__ float4 h0v[16];
    __shared__ float4 h1v[16];
    __shared__ float g0[256];
    __shared__ float g1[256];
    float* h0s = (float*)h0v;
    float* h1s = (float*)h1v;

    const int t = threadIdx.x;
    const bool isA = (t < 256);
    const int j = isA ? t : (t - 256);
    const int gate = j >> 6;  // 0:i 1:f 2:g 3:o

    float wa[64], wb[64];
    float bias = 0.0f;
    if (isA) {
#pragma unroll
        for (int k = 0; k < 64; ++k) wa[k] = w_hh0[j * 64 + k];
#pragma unroll
        for (int k = 0; k < 64; ++k) wb[k] = 0.0f;
    } else {
#pragma unroll
        for (int k = 0; k < 64; ++k) wa[k] = w_ih1[j * 64 + k];
#pragma unroll
        for (int k = 0; k < 64; ++k) wb[k] = w_hh1[j * 64 + k];
        bias = b_ih1[j] + b_hh1[j];
    }

    if (t < 64) h0s[t] = 0.0f;
    else if (t < 128) h1s[t - 64] = 0.0f;
    float c = 0.0f;  // cell state for update threads (t<64: c0[t], t in 64..127: c1[t-64])

    float g_next = isA ? gx0[j] : 0.0f;
    __syncthreads();

#pragma unroll 1
    for (int s = 0; s <= TT; ++s) {
        // ---- phase 1: gate pre-activations + pointwise nonlinearity ----
        if (isA) {
            if (s < TT) {
                float acc = g_next;
                int nxt = (s + 1 < TT) ? (s + 1) : (TT - 1);
                g_next = gx0[nxt * 256 + j];  // prefetch next step
#pragma unroll
                for (int k4 = 0; k4 < 16; ++k4) {
                    float4 h4 = h0v[k4];
                    acc += h4.x * wa[4 * k4 + 0] + h4.y * wa[4 * k4 + 1] +
                           h4.z * wa[4 * k4 + 2] + h4.w * wa[4 * k4 + 3];
                }
                g0[j] = (gate == 2) ? tanh_(acc) : sigm(acc);
            }
        } else {
            if (s >= 1) {
                float acc = bias;
#pragma unroll
                for (int k4 = 0; k4 < 16; ++k4) {
                    float4 h4 = h0v[k4];  // y0 = layer0 output at time s-1
                    acc += h4.x * wa[4 * k4 + 0] + h4.y * wa[4 * k4 + 1] +
                           h4.z * wa[4 * k4 + 2] + h4.w * wa[4 * k4 + 3];
                }
#pragma unroll
                for (int k4 = 0; k4 < 16; ++k4) {
                    float4 h4 = h1v[k4];
                    acc += h4.x * wb[4 * k4 + 0] + h4.y * wb[4 * k4 + 1] +
                           h4.z * wb[4 * k4 + 2] + h4.w * wb[4 * k4 + 3];
                }
                g1[j] = (gate == 2) ? tanh_(acc) : sigm(acc);
            }
        }
        __syncthreads();
        // ---- phase 2: cell/state update ----
        if (t < 64) {
            if (s < TT) {
                float gi = g0[t], gf = g0[64 + t], gg = g0[128 + t], go = g0[192 + t];
                c = gf * c + gi * gg;
                h0s[t] = go * tanh_(c);
            }
        } else if (t < 128) {
            if (s >= 1) {
                int k = t - 64;
                float gi = g1[k], gf = g1[64 + k], gg = g1[128 + k], go = g1[192 + k];
                c = gf * c + gi * gg;
                h1s[k] = go * tanh_(c);
            }
        }
        __syncthreads();
    }

    if (t >= 64 && t < 128) {
        hc_out[t - 64] = h1s[t - 64];  // h1 final
        hc_out[64 + (t - 64)] = c;     // c1 final
    }
}

// Kernel 3: out[0..800000)   = c1 @ w_es.T + b_es   (emb_state)
//           out[800000..1.6M) = h1 @ w_eh.T + b_eh  (emb_hidden)
// 16 lanes per row, one float4 per lane, shfl_xor reduce. 16 rows per 256-thread block.
__global__ __launch_bounds__(256) void proj_kernel(const float* __restrict__ hc,
                                                   const float* __restrict__ w_es,
                                                   const float* __restrict__ b_es,
                                                   const float* __restrict__ w_eh,
                                                   const float* __restrict__ b_eh,
                                                   float* __restrict__ out) {
    __shared__ float4 hv[16];
    __shared__ float4 cv[16];
    const int tid = threadIdx.x;
    if (tid < 16) hv[tid] = ((const float4*)hc)[tid];
    else if (tid < 32) cv[tid - 16] = ((const float4*)(hc + 64))[tid - 16];
    __syncthreads();

    const int lane16 = tid & 15;
    const long r = (long)blockIdx.x * 16 + (tid >> 4);
    const float* w;
    const float* b;
    float4 v;
    long rr;
    if (r < DPROJ) {
        rr = r;
        w = w_es;
        b = b_es;
        v = cv[lane16];
    } else {
        rr = r - DPROJ;
        w = w_eh;
        b = b_eh;
        v = hv[lane16];
    }
    float4 wv = ((const float4*)(w + rr * 64))[lane16];
    float p = wv.x * v.x + wv.y * v.y + wv.z * v.z + wv.w * v.w;
    p += __shfl_xor(p, 1);
    p += __shfl_xor(p, 2);
    p += __shfl_xor(p, 4);
    p += __shfl_xor(p, 8);
    if (lane16 == 0) out[r] = p + b[rr];
}

extern "C" void kernel_launch(void* const* d_in, const int* in_sizes, int n_in,
                              void* d_out, int out_size, void* d_ws, size_t ws_size,
                              hipStream_t stream) {
    const float* x = (const float*)d_in[0];
    const float* w_ih0 = (const float*)d_in[1];
    const float* w_hh0 = (const float*)d_in[2];
    const float* b_ih0 = (const float*)d_in[3];
    const float* b_hh0 = (const float*)d_in[4];
    const float* w_ih1 = (const float*)d_in[5];
    const float* w_hh1 = (const float*)d_in[6];
    const float* b_ih1 = (const float*)d_in[7];
    const float* b_hh1 = (const float*)d_in[8];
    const float* w_eh = (const float*)d_in[9];
    const float* b_eh = (const float*)d_in[10];
    const float* w_es = (const float*)d_in[11];
    const float* b_es = (const float*)d_in[12];
    float* out = (float*)d_out;

    float* gx0 = (float*)d_ws;           // 4096*256 floats = 4 MB
    float* hc = gx0 + 4096 * 256;        // 128 floats: [h1(64), c1(64)]

    gx0_kernel<<<4096, 256, 0, stream>>>(x, w_ih0, b_ih0, b_hh0, gx0);
    lstm_kernel<<<1, 512, 0, stream>>>(gx0, w_hh0, w_ih1, w_hh1, b_ih1, b_hh1, hc);
    proj_kernel<<<DPROJ * 2 / 16, 256, 0, stream>>>(hc, w_es, b_es, w_eh, b_eh, out);
}

// Round 2
// 2889.153 us; speedup vs baseline: 1.5137x; 1.5137x over previous
//
#include <hip/hip_runtime.h>

#define TT 4096
#define DPROJ 800000

typedef float v2f __attribute__((ext_vector_type(2)));

__device__ __forceinline__ float fexp2(float x) { return __builtin_amdgcn_exp2f(x); }
__device__ __forceinline__ float frcp(float x) { return __builtin_amdgcn_rcpf(x); }

__device__ __forceinline__ v2f pkfma(v2f a, v2f b, v2f c) {
    asm("v_pk_fma_f32 %0, %1, %2, %0" : "+v"(c) : "v"(a), "v"(b));
    return c;
}

template <int CTRL>
__device__ __forceinline__ float dppf(float x) {
    return __int_as_float(
        __builtin_amdgcn_update_dpp(0, __float_as_int(x), CTRL, 0xF, 0xF, true));
}

// barrier WITHOUT the vmcnt(0) drain __syncthreads would emit: keeps the
// gx0 prefetch loads in flight across steps. lgkmcnt(0) makes LDS writes
// visible to other waves before the barrier.
__device__ __forceinline__ void barrier_nd() {
    asm volatile("s_waitcnt lgkmcnt(0)\n\ts_barrier" ::: "memory");
}

// Kernel 1: gx0p[t][u] = float4(gates i,f,g,o pre-activation input part for unit u)
// i.e. gx0p[t*256 + u*4 + g] = dot(x[t,:], w_ih0[g*64+u,:]) + b_ih0 + b_hh0
__global__ __launch_bounds__(256) void gx0_kernel(const float* __restrict__ x,
                                                  const float* __restrict__ w_ih0,
                                                  const float* __restrict__ b_ih0,
                                                  const float* __restrict__ b_hh0,
                                                  float* __restrict__ gx0p) {
    __shared__ __align__(16) float xs[32];
    const int t = blockIdx.x;
    const int j = threadIdx.x;
    if (j < 32) xs[j] = x[t * 32 + j];
    __syncthreads();
    const float4* w4 = (const float4*)(w_ih0 + j * 32);
    const float4* x4 = (const float4*)xs;
    float acc = b_ih0[j] + b_hh0[j];
#pragma unroll
    for (int u = 0; u < 8; ++u) {
        float4 w = w4[u];
        float4 xv = x4[u];
        acc += w.x * xv.x + w.y * xv.y + w.z * xv.z + w.w * xv.w;
    }
    const int g = j >> 6;   // gate
    const int uu = j & 63;  // unit
    gx0p[t * 256 + uu * 4 + g] = acc;
}

// Kernel 2: sequential 2-layer LSTM. 512 threads = 8 waves on 1 CU.
// Waves 0-3 (A): layer0 at time i.  Waves 4-7 (B): layer1 at time i-1.
// Lane (u = j>>2, q = j&3): holds all 4 gate weight rows of unit u over
// k in [16q, 16q+16). Quad DPP butterfly completes the dots; one barrier/step.
__global__ __launch_bounds__(512, 2) void lstm_kernel(const float* __restrict__ gx0,
                                                      const float* __restrict__ w_hh0,
                                                      const float* __restrict__ w_ih1,
                                                      const float* __restrict__ w_hh1,
                                                      const float* __restrict__ b_ih1,
                                                      const float* __restrict__ b_hh1,
                                                      float* __restrict__ hc_out) {
    __shared__ __align__(16) float h0buf[2][64];
    __shared__ __align__(16) float h1buf[2][64];

    const int t = threadIdx.x;
    const int j = t & 255;
    const int u = j >> 2;
    const int q = j & 3;
    const int qk = q * 16;
    const bool qg = (q == 2);
    const float kmul = qg ? -2.885390082f : -1.442695041f;  // -2/log2e, -1/log2e... (-log2(e)*m)
    const float mm = qg ? 2.0f : 1.0f;
    const float dd = qg ? 1.0f : 0.0f;
    float cst = 0.0f;

    if (t < 256) {
        // ================= group A: layer 0 =================
        v2f w0[8], w1[8], w2[8], w3[8];
#pragma unroll
        for (int cc = 0; cc < 8; ++cc) {
            w0[cc] = *(const v2f*)(w_hh0 + (0 * 64 + u) * 64 + qk + 2 * cc);
            w1[cc] = *(const v2f*)(w_hh0 + (1 * 64 + u) * 64 + qk + 2 * cc);
            w2[cc] = *(const v2f*)(w_hh0 + (2 * 64 + u) * 64 + qk + 2 * cc);
            w3[cc] = *(const v2f*)(w_hh0 + (3 * 64 + u) * 64 + qk + 2 * cc);
        }
        const float4* gp = ((const float4*)gx0) + u;
        float4 pf0 = gp[0 * 64];
        float4 pf1 = gp[1 * 64];
        float4 pf2 = gp[2 * 64];
        float4 pf3 = gp[3 * 64];
        if (q == 0) h0buf[1][u] = 0.0f;
        barrier_nd();  // (1) init visible

#define A_STEP(PF, RDP, WRP, ROWI)                                                      \
    {                                                                                   \
        const v2f* hp = (const v2f*)&h0buf[RDP][qk];                                    \
        v2f a0 = {0.0f, 0.0f}, a1 = a0, a2 = a0, a3 = a0;                               \
        _Pragma("unroll") for (int cc = 0; cc < 8; ++cc) {                              \
            v2f hv = hp[cc];                                                            \
            a0 = pkfma(w0[cc], hv, a0);                                                 \
            a1 = pkfma(w1[cc], hv, a1);                                                 \
            a2 = pkfma(w2[cc], hv, a2);                                                 \
            a3 = pkfma(w3[cc], hv, a3);                                                 \
        }                                                                               \
        float G0 = a0.x + a0.y, G1 = a1.x + a1.y, G2 = a2.x + a2.y, G3 = a3.x + a3.y;   \
        G0 += dppf<0xB1>(G0); G1 += dppf<0xB1>(G1);                                     \
        G2 += dppf<0xB1>(G2); G3 += dppf<0xB1>(G3);                                     \
        G0 += dppf<0x4E>(G0); G1 += dppf<0x4E>(G1);                                     \
        G2 += dppf<0x4E>(G2); G3 += dppf<0x4E>(G3);                                     \
        G0 += PF.x; G1 += PF.y; G2 += PF.z; G3 += PF.w;                                 \
        float arg = q == 0 ? G0 : (q == 1 ? G1 : (q == 2 ? G2 : G3));                   \
        float act = __builtin_fmaf(mm, frcp(1.0f + fexp2(kmul * arg)), -dd);            \
        float gi = dppf<0x00>(act), gf = dppf<0x55>(act);                               \
        float gg = dppf<0xAA>(act), go = dppf<0xFF>(act);                               \
        cst = __builtin_fmaf(gf, cst, gi * gg);                                         \
        float th = __builtin_fmaf(2.0f, frcp(1.0f + fexp2(-2.885390082f * cst)), -1.0f);\
        float hnew = go * th;                                                           \
        if (q == 0) h0buf[WRP][u] = hnew;                                               \
        PF = gp[(ROWI) * 64];                                                           \
        barrier_nd();                                                                   \
    }

        A_STEP(pf0, 1, 0, 4)  // i = 0 peeled
#pragma unroll 1
        for (int b = 0; b < 1023; ++b) {  // i = 4b+1 .. 4b+4
            const int i4 = 4 * b;
            A_STEP(pf1, 0, 1, i4 + 5)
            A_STEP(pf2, 1, 0, i4 + 6)
            A_STEP(pf3, 0, 1, i4 + 7)
            A_STEP(pf0, 1, 0, (i4 + 8 < TT ? i4 + 8 : TT - 1))
        }
        A_STEP(pf1, 0, 1, TT - 1)  // i = 4093
        A_STEP(pf2, 1, 0, TT - 1)  // i = 4094
        A_STEP(pf3, 0, 1, TT - 1)  // i = 4095
        barrier_nd();              // i = 4096 (B-only step)
    } else {
        // ================= group B: layer 1 =================
        v2f wi0[8], wi1[8], wi2[8], wi3[8];
        v2f wh0[8], wh1[8], wh2[8], wh3[8];
#pragma unroll
        for (int cc = 0; cc < 8; ++cc) {
            wi0[cc] = *(const v2f*)(w_ih1 + (0 * 64 + u) * 64 + qk + 2 * cc);
            wi1[cc] = *(const v2f*)(w_ih1 + (1 * 64 + u) * 64 + qk + 2 * cc);
            wi2[cc] = *(const v2f*)(w_ih1 + (2 * 64 + u) * 64 + qk + 2 * cc);
            wi3[cc] = *(const v2f*)(w_ih1 + (3 * 64 + u) * 64 + qk + 2 * cc);
            wh0[cc] = *(const v2f*)(w_hh1 + (0 * 64 + u) * 64 + qk + 2 * cc);
            wh1[cc] = *(const v2f*)(w_hh1 + (1 * 64 + u) * 64 + qk + 2 * cc);
            wh2[cc] = *(const v2f*)(w_hh1 + (2 * 64 + u) * 64 + qk + 2 * cc);
            wh3[cc] = *(const v2f*)(w_hh1 + (3 * 64 + u) * 64 + qk + 2 * cc);
        }
        float4 bias;
        bias.x = b_ih1[0 * 64 + u] + b_hh1[0 * 64 + u];
        bias.y = b_ih1[1 * 64 + u] + b_hh1[1 * 64 + u];
        bias.z = b_ih1[2 * 64 + u] + b_hh1[2 * 64 + u];
        bias.w = b_ih1[3 * 64 + u] + b_hh1[3 * 64 + u];
        float hlast = 0.0f;
        if (q == 0) h1buf[1][u] = 0.0f;
        barrier_nd();  // pairs with A init barrier
        barrier_nd();  // pairs with A's i=0 step

#define B_STEP(P)                                                                       \
    {                                                                                   \
        const v2f* hp0 = (const v2f*)&h0buf[P][qk];                                     \
        const v2f* hp1 = (const v2f*)&h1buf[(P) ^ 1][qk];                               \
        v2f a0 = {0.0f, 0.0f}, a1 = a0, a2 = a0, a3 = a0;                               \
        v2f c0 = a0, c1 = a0, c2 = a0, c3 = a0;                                         \
        _Pragma("unroll") for (int cc = 0; cc < 8; ++cc) {                              \
            v2f hv0 = hp0[cc];                                                          \
            v2f hv1 = hp1[cc];                                                          \
            a0 = pkfma(wi0[cc], hv0, a0);                                               \
            a1 = pkfma(wi1[cc], hv0, a1);                                               \
            a2 = pkfma(wi2[cc], hv0, a2);                                               \
            a3 = pkfma(wi3[cc], hv0, a3);                                               \
            c0 = pkfma(wh0[cc], hv1, c0);                                               \
            c1 = pkfma(wh1[cc], hv1, c1);                                               \
            c2 = pkfma(wh2[cc], hv1, c2);                                               \
            c3 = pkfma(wh3[cc], hv1, c3);                                               \
        }                                                                               \
        float G0 = (a0.x + a0.y) + (c0.x + c0.y);                                       \
        float G1 = (a1.x + a1.y) + (c1.x + c1.y);                                       \
        float G2 = (a2.x + a2.y) + (c2.x + c2.y);                                       \
        float G3 = (a3.x + a3.y) + (c3.x + c3.y);                                       \
        G0 += dppf<0xB1>(G0); G1 += dppf<0xB1>(G1);                                     \
        G2 += dppf<0xB1>(G2); G3 += dppf<0xB1>(G3);                                     \
        G0 += dppf<0x4E>(G0); G1 += dppf<0x4E>(G1);                                     \
        G2 += dppf<0x4E>(G2); G3 += dppf<0x4E>(G3);                                     \
        G0 += bias.x; G1 += bias.y; G2 += bias.z; G3 += bias.w;                         \
        float arg = q == 0 ? G0 : (q == 1 ? G1 : (q == 2 ? G2 : G3));                   \
        float act = __builtin_fmaf(mm, frcp(1.0f + fexp2(kmul * arg)), -dd);            \
        float gi = dppf<0x00>(act), gf = dppf<0x55>(act);                               \
        float gg = dppf<0xAA>(act), go = dppf<0xFF>(act);                               \
        cst = __builtin_fmaf(gf, cst, gi * gg);                                         \
        float th = __builtin_fmaf(2.0f, frcp(1.0f + fexp2(-2.885390082f * cst)), -1.0f);\
        float hnew = go * th;                                                           \
        hlast = hnew;                                                                   \
        if (q == 0) h1buf[P][u] = hnew;                                                 \
        barrier_nd();                                                                   \
    }

#pragma unroll 1
        for (int b = 0; b < 1023; ++b) {  // i = 4b+1 .. 4b+4  -> h1_{i-1}
            B_STEP(0)
            B_STEP(1)
            B_STEP(0)
            B_STEP(1)
        }
        B_STEP(0)  // i = 4093
        B_STEP(1)  // i = 4094
        B_STEP(0)  // i = 4095
        B_STEP(1)  // i = 4096 -> h1_4095 (final)
        if (q == 0) {
            hc_out[u] = hlast;      // h1 final
            hc_out[64 + u] = cst;   // c1 final
        }
    }
}

// Kernel 3: out[0..800000) = c1 @ w_es.T + b_es ; out[800000..1.6M) = h1 @ w_eh.T + b_eh
// 4 lanes per output row (16 floats each), DPP quad reduce, 64 rows/block.
__global__ __launch_bounds__(256) void proj_kernel(const float* __restrict__ hc,
                                                   const float* __restrict__ w_es,
                                                   const float* __restrict__ b_es,
                                                   const float* __restrict__ w_eh,
                                                   const float* __restrict__ b_eh,
                                                   float* __restrict__ out) {
    __shared__ __align__(16) float hv[64];
    __shared__ __align__(16) float cv[64];
    const int tid = threadIdx.x;
    if (tid < 64) hv[tid] = hc[tid];
    else if (tid < 128) cv[tid - 64] = hc[tid];
    __syncthreads();

    const int p = tid & 3;
    const long r = (long)blockIdx.x * 64 + (tid >> 2);
    const float* w;
    const float* bb;
    const float* v;
    long rr;
    if (r < DPROJ) {
        rr = r;
        w = w_es;
        bb = b_es;
        v = cv;
    } else {
        rr = r - DPROJ;
        w = w_eh;
        bb = b_eh;
        v = hv;
    }
    const float4* wp = (const float4*)(w + rr * 64 + p * 16);
    const float4* vp = (const float4*)(v + p * 16);
    v2f s = {0.0f, 0.0f};
#pragma unroll
    for (int cc = 0; cc < 4; ++cc) {
        float4 wv = wp[cc];
        float4 vv = vp[cc];
        v2f w01 = {wv.x, wv.y}, v01 = {vv.x, vv.y};
        v2f w23 = {wv.z, wv.w}, v23 = {vv.z, vv.w};
        s = pkfma(w01, v01, s);
        s = pkfma(w23, v23, s);
    }
    float sum = s.x + s.y;
    sum += dppf<0xB1>(sum);
    sum += dppf<0x4E>(sum);
    if (p == 0) out[r] = sum + bb[rr];
}

extern "C" void kernel_launch(void* const* d_in, const int* in_sizes, int n_in,
                              void* d_out, int out_size, void* d_ws, size_t ws_size,
                              hipStream_t stream) {
    const float* x = (const float*)d_in[0];
    const float* w_ih0 = (const float*)d_in[1];
    const float* w_hh0 = (const float*)d_in[2];
    const float* b_ih0 = (const float*)d_in[3];
    const float* b_hh0 = (const float*)d_in[4];
    const float* w_ih1 = (const float*)d_in[5];
    const float* w_hh1 = (const float*)d_in[6];
    const float* b_ih1 = (const float*)d_in[7];
    const float* b_hh1 = (const float*)d_in[8];
    const float* w_eh = (const float*)d_in[9];
    const float* b_eh = (const float*)d_in[10];
    const float* w_es = (const float*)d_in[11];
    const float* b_es = (const float*)d_in[12];
    float* out = (float*)d_out;

    float* gx0 = (float*)d_ws;        // 4096*256 floats = 4 MB (permuted float4-per-unit)
    float* hc = gx0 + 4096 * 256;     // 128 floats: [h1(64), c1(64)]

    gx0_kernel<<<4096, 256, 0, stream>>>(x, w_ih0, b_ih0, b_hh0, gx0);
    lstm_kernel<<<1, 512, 0, stream>>>(gx0, w_hh0, w_ih1, w_hh1, b_ih1, b_hh1, hc);
    proj_kernel<<<2 * DPROJ / 64, 256, 0, stream>>>(hc, w_es, b_es, w_eh, b_eh, out);
}

// Round 3
// 2414.824 us; speedup vs baseline: 1.8110x; 1.1964x over previous
//
#include <hip/hip_runtime.h>

#define TT 4096
#define DPROJ 800000

typedef float v2f __attribute__((ext_vector_type(2)));
typedef float v4f __attribute__((ext_vector_type(4)));

__device__ __forceinline__ float fexp2(float x) { return __builtin_amdgcn_exp2f(x); }
__device__ __forceinline__ float frcp(float x) { return __builtin_amdgcn_rcpf(x); }

__device__ __forceinline__ v2f pkfma(v2f a, v2f b, v2f c) {
    asm("v_pk_fma_f32 %0, %1, %2, %0" : "+v"(c) : "v"(a), "v"(b));
    return c;
}

template <int CTRL>
__device__ __forceinline__ float dppf(float x) {
    return __int_as_float(
        __builtin_amdgcn_update_dpp(0, __float_as_int(x), CTRL, 0xF, 0xF, true));
}

__device__ __forceinline__ v2f lo2(v4f v) { return __builtin_shufflevector(v, v, 0, 1); }
__device__ __forceinline__ v2f hi2(v4f v) { return __builtin_shufflevector(v, v, 2, 3); }

// barrier WITHOUT the vmcnt(0) drain __syncthreads would emit.
__device__ __forceinline__ void barrier_nd() {
    asm volatile("s_waitcnt lgkmcnt(0)\n\ts_barrier" ::: "memory");
}

// ---- named-register bundles (NO allocas -> NO scratch) ----
#define WDECL(nm) v2f nm##0, nm##1, nm##2, nm##3, nm##4, nm##5, nm##6, nm##7;
#define WLOAD(nm, base)                                                      \
    {                                                                        \
        const v4f* q_ = (const v4f*)(base);                                  \
        v4f A_ = q_[0], B_ = q_[1], C_ = q_[2], D_ = q_[3];                  \
        nm##0 = lo2(A_); nm##1 = hi2(A_); nm##2 = lo2(B_); nm##3 = hi2(B_);  \
        nm##4 = lo2(C_); nm##5 = hi2(C_); nm##6 = lo2(D_); nm##7 = hi2(D_);  \
    }
#define WDOT(acc, nm, h)                                                     \
    acc = pkfma(nm##0, h##0, acc); acc = pkfma(nm##1, h##1, acc);            \
    acc = pkfma(nm##2, h##2, acc); acc = pkfma(nm##3, h##3, acc);            \
    acc = pkfma(nm##4, h##4, acc); acc = pkfma(nm##5, h##5, acc);            \
    acc = pkfma(nm##6, h##6, acc); acc = pkfma(nm##7, h##7, acc);
#define HREAD(h, ptr)                                                        \
    v2f h##0, h##1, h##2, h##3, h##4, h##5, h##6, h##7;                      \
    {                                                                        \
        const v4f* p_ = (const v4f*)(ptr);                                   \
        v4f ha_ = p_[0], hb_ = p_[1], hc_ = p_[2], hd_ = p_[3];              \
        h##0 = lo2(ha_); h##1 = hi2(ha_); h##2 = lo2(hb_); h##3 = hi2(hb_);  \
        h##4 = lo2(hc_); h##5 = hi2(hc_); h##6 = lo2(hd_); h##7 = hi2(hd_);  \
    }

// Kernel 1: gx0p[t*256 + u*4 + g] = dot(x[t,:], w_ih0[g*64+u,:]) + b_ih0 + b_hh0
__global__ __launch_bounds__(256) void gx0_kernel(const float* __restrict__ x,
                                                  const float* __restrict__ w_ih0,
                                                  const float* __restrict__ b_ih0,
                                                  const float* __restrict__ b_hh0,
                                                  float* __restrict__ gx0p) {
    __shared__ __align__(16) float xs[32];
    const int t = blockIdx.x;
    const int j = threadIdx.x;
    if (j < 32) xs[j] = x[t * 32 + j];
    __syncthreads();
    const float4* w4 = (const float4*)(w_ih0 + j * 32);
    const float4* x4 = (const float4*)xs;
    float acc = b_ih0[j] + b_hh0[j];
#pragma unroll
    for (int u = 0; u < 8; ++u) {
        float4 w = w4[u];
        float4 xv = x4[u];
        acc += w.x * xv.x + w.y * xv.y + w.z * xv.z + w.w * xv.w;
    }
    const int g = j >> 6;
    const int uu = j & 63;
    gx0p[t * 256 + uu * 4 + g] = acc;
}

// Kernel 2: sequential 2-layer LSTM. 512 threads = 8 waves on 1 CU.
// Waves 0-3 (A): layer0 time i.  Waves 4-7 (B): layer1 time i-1.
// Lane (u = j>>2, q = j&3): all 4 gate rows of unit u over k in [16q,16q+16).
__global__ __launch_bounds__(512, 2) void lstm_kernel(const float* __restrict__ gx0,
                                                      const float* __restrict__ w_hh0,
                                                      const float* __restrict__ w_ih1,
                                                      const float* __restrict__ w_hh1,
                                                      const float* __restrict__ b_ih1,
                                                      const float* __restrict__ b_hh1,
                                                      float* __restrict__ hc_out) {
    __shared__ __align__(16) float h0buf[2][64];
    __shared__ __align__(16) float h1buf[2][64];

    const int t = threadIdx.x;
    const int j = t & 255;
    const int u = j >> 2;
    const int q = j & 3;
    const int qk = q * 16;
    const bool qg = (q == 2);
    const float kmul = qg ? -2.885390082f : -1.442695041f;
    const float mm = qg ? 2.0f : 1.0f;
    const float dd = qg ? 1.0f : 0.0f;
    const v2f Z2 = {0.0f, 0.0f};
    float cst = 0.0f;

    if (t < 256) {
        // ================= group A: layer 0 =================
        WDECL(wA0_) WDECL(wA1_) WDECL(wA2_) WDECL(wA3_)
        WLOAD(wA0_, w_hh0 + (0 * 64 + u) * 64 + qk)
        WLOAD(wA1_, w_hh0 + (1 * 64 + u) * 64 + qk)
        WLOAD(wA2_, w_hh0 + (2 * 64 + u) * 64 + qk)
        WLOAD(wA3_, w_hh0 + (3 * 64 + u) * 64 + qk)
        const float4* gp = ((const float4*)gx0) + u;
        float4 pf0 = gp[0 * 64];
        float4 pf1 = gp[1 * 64];
        float4 pf2 = gp[2 * 64];
        float4 pf3 = gp[3 * 64];
        if (q == 0) h0buf[1][u] = 0.0f;
        barrier_nd();  // init visible

#define A_STEP(PF, RDP, WRP, ROWI)                                                      \
    {                                                                                   \
        HREAD(h_, &h0buf[RDP][qk])                                                      \
        v2f a0 = Z2, a1 = Z2, a2 = Z2, a3 = Z2;                                         \
        WDOT(a0, wA0_, h_) WDOT(a1, wA1_, h_) WDOT(a2, wA2_, h_) WDOT(a3, wA3_, h_)     \
        float G0 = a0.x + a0.y, G1 = a1.x + a1.y, G2 = a2.x + a2.y, G3 = a3.x + a3.y;   \
        G0 += dppf<0xB1>(G0); G1 += dppf<0xB1>(G1);                                     \
        G2 += dppf<0xB1>(G2); G3 += dppf<0xB1>(G3);                                     \
        G0 += dppf<0x4E>(G0); G1 += dppf<0x4E>(G1);                                     \
        G2 += dppf<0x4E>(G2); G3 += dppf<0x4E>(G3);                                     \
        G0 += PF.x; G1 += PF.y; G2 += PF.z; G3 += PF.w;                                 \
        float arg = q == 0 ? G0 : (q == 1 ? G1 : (q == 2 ? G2 : G3));                   \
        float act = __builtin_fmaf(mm, frcp(1.0f + fexp2(kmul * arg)), -dd);            \
        float gi = dppf<0x00>(act), gf = dppf<0x55>(act);                               \
        float gg = dppf<0xAA>(act), go = dppf<0xFF>(act);                               \
        cst = __builtin_fmaf(gf, cst, gi * gg);                                         \
        float th = __builtin_fmaf(2.0f, frcp(1.0f + fexp2(-2.885390082f * cst)), -1.0f);\
        float hnew = go * th;                                                           \
        if (q == 0) h0buf[WRP][u] = hnew;                                               \
        PF = gp[(ROWI) * 64];                                                           \
        barrier_nd();                                                                   \
    }

        A_STEP(pf0, 1, 0, 4)  // i = 0
#pragma unroll 1
        for (int b = 0; b < 1023; ++b) {  // i = 4b+1 .. 4b+4
            const int i4 = 4 * b;
            A_STEP(pf1, 0, 1, i4 + 5)
            A_STEP(pf2, 1, 0, i4 + 6)
            A_STEP(pf3, 0, 1, i4 + 7)
            A_STEP(pf0, 1, 0, (i4 + 8 < TT ? i4 + 8 : TT - 1))
        }
        A_STEP(pf1, 0, 1, TT - 1)  // i = 4093
        A_STEP(pf2, 1, 0, TT - 1)  // i = 4094
        A_STEP(pf3, 0, 1, TT - 1)  // i = 4095
        barrier_nd();              // i = 4096 (B-only step)
    } else {
        // ================= group B: layer 1 =================
        WDECL(wi0_) WDECL(wi1_) WDECL(wi2_) WDECL(wi3_)
        WDECL(wh0_) WDECL(wh1_) WDECL(wh2_) WDECL(wh3_)
        WLOAD(wi0_, w_ih1 + (0 * 64 + u) * 64 + qk)
        WLOAD(wi1_, w_ih1 + (1 * 64 + u) * 64 + qk)
        WLOAD(wi2_, w_ih1 + (2 * 64 + u) * 64 + qk)
        WLOAD(wi3_, w_ih1 + (3 * 64 + u) * 64 + qk)
        WLOAD(wh0_, w_hh1 + (0 * 64 + u) * 64 + qk)
        WLOAD(wh1_, w_hh1 + (1 * 64 + u) * 64 + qk)
        WLOAD(wh2_, w_hh1 + (2 * 64 + u) * 64 + qk)
        WLOAD(wh3_, w_hh1 + (3 * 64 + u) * 64 + qk)
        float4 bias;
        bias.x = b_ih1[0 * 64 + u] + b_hh1[0 * 64 + u];
        bias.y = b_ih1[1 * 64 + u] + b_hh1[1 * 64 + u];
        bias.z = b_ih1[2 * 64 + u] + b_hh1[2 * 64 + u];
        bias.w = b_ih1[3 * 64 + u] + b_hh1[3 * 64 + u];
        float hlast = 0.0f;
        if (q == 0) h1buf[1][u] = 0.0f;
        barrier_nd();  // pairs with A init barrier
        barrier_nd();  // pairs with A's i=0 step

#define B_STEP(P)                                                                       \
    {                                                                                   \
        HREAD(h_, &h0buf[P][qk])                                                        \
        HREAD(k_, &h1buf[(P) ^ 1][qk])                                                  \
        v2f a0 = Z2, a1 = Z2, a2 = Z2, a3 = Z2;                                         \
        v2f c0 = Z2, c1 = Z2, c2 = Z2, c3 = Z2;                                         \
        WDOT(a0, wi0_, h_) WDOT(a1, wi1_, h_) WDOT(a2, wi2_, h_) WDOT(a3, wi3_, h_)     \
        WDOT(c0, wh0_, k_) WDOT(c1, wh1_, k_) WDOT(c2, wh2_, k_) WDOT(c3, wh3_, k_)     \
        float G0 = (a0.x + a0.y) + (c0.x + c0.y);                                       \
        float G1 = (a1.x + a1.y) + (c1.x + c1.y);                                       \
        float G2 = (a2.x + a2.y) + (c2.x + c2.y);                                       \
        float G3 = (a3.x + a3.y) + (c3.x + c3.y);                                       \
        G0 += dppf<0xB1>(G0); G1 += dppf<0xB1>(G1);                                     \
        G2 += dppf<0xB1>(G2); G3 += dppf<0xB1>(G3);                                     \
        G0 += dppf<0x4E>(G0); G1 += dppf<0x4E>(G1);                                     \
        G2 += dppf<0x4E>(G2); G3 += dppf<0x4E>(G3);                                     \
        G0 += bias.x; G1 += bias.y; G2 += bias.z; G3 += bias.w;                         \
        float arg = q == 0 ? G0 : (q == 1 ? G1 : (q == 2 ? G2 : G3));                   \
        float act = __builtin_fmaf(mm, frcp(1.0f + fexp2(kmul * arg)), -dd);            \
        float gi = dppf<0x00>(act), gf = dppf<0x55>(act);                               \
        float gg = dppf<0xAA>(act), go = dppf<0xFF>(act);                               \
        cst = __builtin_fmaf(gf, cst, gi * gg);                                         \
        float th = __builtin_fmaf(2.0f, frcp(1.0f + fexp2(-2.885390082f * cst)), -1.0f);\
        float hnew = go * th;                                                           \
        hlast = hnew;                                                                   \
        if (q == 0) h1buf[P][u] = hnew;                                                 \
        barrier_nd();                                                                   \
    }

#pragma unroll 1
        for (int b = 0; b < 1023; ++b) {
            B_STEP(0)
            B_STEP(1)
            B_STEP(0)
            B_STEP(1)
        }
        B_STEP(0)  // i = 4093
        B_STEP(1)  // i = 4094
        B_STEP(0)  // i = 4095
        B_STEP(1)  // i = 4096 -> h1_4095 (final)
        if (q == 0) {
            hc_out[u] = hlast;
            hc_out[64 + u] = cst;
        }
    }
}

// Kernel 3: out[0..800000) = c1 @ w_es.T + b_es ; out[800000..1.6M) = h1 @ w_eh.T + b_eh
__global__ __launch_bounds__(256) void proj_kernel(const float* __restrict__ hc,
                                                   const float* __restrict__ w_es,
                                                   const float* __restrict__ b_es,
                                                   const float* __restrict__ w_eh,
                                                   const float* __restrict__ b_eh,
                                                   float* __restrict__ out) {
    __shared__ __align__(16) float hv[64];
    __shared__ __align__(16) float cv[64];
    const int tid = threadIdx.x;
    if (tid < 64) hv[tid] = hc[tid];
    else if (tid < 128) cv[tid - 64] = hc[tid];
    __syncthreads();

    const int p = tid & 3;
    const long r = (long)blockIdx.x * 64 + (tid >> 2);
    const float* w;
    const float* bb;
    const float* v;
    long rr;
    if (r < DPROJ) {
        rr = r;
        w = w_es;
        bb = b_es;
        v = cv;
    } else {
        rr = r - DPROJ;
        w = w_eh;
        bb = b_eh;
        v = hv;
    }
    const float4* wp = (const float4*)(w + rr * 64 + p * 16);
    const float4* vp = (const float4*)(v + p * 16);
    v2f s = {0.0f, 0.0f};
#pragma unroll
    for (int cc = 0; cc < 4; ++cc) {
        float4 wv = wp[cc];
        float4 vv = vp[cc];
        v2f w01 = {wv.x, wv.y}, v01 = {vv.x, vv.y};
        v2f w23 = {wv.z, wv.w}, v23 = {vv.z, vv.w};
        s = pkfma(w01, v01, s);
        s = pkfma(w23, v23, s);
    }
    float sum = s.x + s.y;
    sum += dppf<0xB1>(sum);
    sum += dppf<0x4E>(sum);
    if (p == 0) out[r] = sum + bb[rr];
}

extern "C" void kernel_launch(void* const* d_in, const int* in_sizes, int n_in,
                              void* d_out, int out_size, void* d_ws, size_t ws_size,
                              hipStream_t stream) {
    const float* x = (const float*)d_in[0];
    const float* w_ih0 = (const float*)d_in[1];
    const float* w_hh0 = (const float*)d_in[2];
    const float* b_ih0 = (const float*)d_in[3];
    const float* b_hh0 = (const float*)d_in[4];
    const float* w_ih1 = (const float*)d_in[5];
    const float* w_hh1 = (const float*)d_in[6];
    const float* b_ih1 = (const float*)d_in[7];
    const float* b_hh1 = (const float*)d_in[8];
    const float* w_eh = (const float*)d_in[9];
    const float* b_eh = (const float*)d_in[10];
    const float* w_es = (const float*)d_in[11];
    const float* b_es = (const float*)d_in[12];
    float* out = (float*)d_out;

    float* gx0 = (float*)d_ws;     // 4096*256 floats = 4 MB (permuted float4-per-unit)
    float* hc = gx0 + 4096 * 256;  // 128 floats: [h1(64), c1(64)]

    gx0_kernel<<<4096, 256, 0, stream>>>(x, w_ih0, b_ih0, b_hh0, gx0);
    lstm_kernel<<<1, 512, 0, stream>>>(gx0, w_hh0, w_ih1, w_hh1, b_ih1, b_hh1, hc);
    proj_kernel<<<2 * DPROJ / 64, 256, 0, stream>>>(hc, w_es, b_es, w_eh, b_eh, out);
}

// Round 4
// 2352.908 us; speedup vs baseline: 1.8587x; 1.0263x over previous
//
#include <hip/hip_runtime.h>

#define TT 4096
#define DPROJ 800000

typedef float v2f __attribute__((ext_vector_type(2)));
typedef float v4f __attribute__((ext_vector_type(4)));

__device__ __forceinline__ float fexp2(float x) { return __builtin_amdgcn_exp2f(x); }
__device__ __forceinline__ float frcp(float x) { return __builtin_amdgcn_rcpf(x); }

__device__ __forceinline__ v2f pkfma(v2f a, v2f b, v2f c) {
    asm("v_pk_fma_f32 %0, %1, %2, %0" : "+v"(c) : "v"(a), "v"(b));
    return c;
}

template <int CTRL>
__device__ __forceinline__ float dppf(float x) {
    return __int_as_float(
        __builtin_amdgcn_update_dpp(0, __float_as_int(x), CTRL, 0xF, 0xF, true));
}

__device__ __forceinline__ v2f lo2(v4f v) { return __builtin_shufflevector(v, v, 0, 1); }
__device__ __forceinline__ v2f hi2(v4f v) { return __builtin_shufflevector(v, v, 2, 3); }

// barrier WITHOUT the vmcnt(0) drain __syncthreads would emit.
__device__ __forceinline__ void barrier_nd() {
    asm volatile("s_waitcnt lgkmcnt(0)\n\ts_barrier" ::: "memory");
}

// ---- named-register bundles (NO allocas -> NO scratch) ----
#define WDECL(nm) v2f nm##0, nm##1, nm##2, nm##3, nm##4, nm##5, nm##6, nm##7;
#define WLOAD(nm, base)                                                      \
    {                                                                        \
        const v4f* q_ = (const v4f*)(base);                                  \
        v4f A_ = q_[0], B_ = q_[1], C_ = q_[2], D_ = q_[3];                  \
        nm##0 = lo2(A_); nm##1 = hi2(A_); nm##2 = lo2(B_); nm##3 = hi2(B_);  \
        nm##4 = lo2(C_); nm##5 = hi2(C_); nm##6 = lo2(D_); nm##7 = hi2(D_);  \
    }
#define WDOT(acc, nm, h)                                                     \
    acc = pkfma(nm##0, h##0, acc); acc = pkfma(nm##1, h##1, acc);            \
    acc = pkfma(nm##2, h##2, acc); acc = pkfma(nm##3, h##3, acc);            \
    acc = pkfma(nm##4, h##4, acc); acc = pkfma(nm##5, h##5, acc);            \
    acc = pkfma(nm##6, h##6, acc); acc = pkfma(nm##7, h##7, acc);
#define HREAD(h, ptr)                                                        \
    v2f h##0, h##1, h##2, h##3, h##4, h##5, h##6, h##7;                      \
    {                                                                        \
        const v4f* p_ = (const v4f*)(ptr);                                   \
        v4f ha_ = p_[0], hb_ = p_[1], hc_ = p_[2], hd_ = p_[3];              \
        h##0 = lo2(ha_); h##1 = hi2(ha_); h##2 = lo2(hb_); h##3 = hi2(hb_);  \
        h##4 = lo2(hc_); h##5 = hi2(hc_); h##6 = lo2(hd_); h##7 = hi2(hd_);  \
    }

// Kernel 1: gx0p[t*256 + u*4 + g] = dot(x[t,:], w_ih0[g*64+u,:]) + b_ih0 + b_hh0
__global__ __launch_bounds__(256) void gx0_kernel(const float* __restrict__ x,
                                                  const float* __restrict__ w_ih0,
                                                  const float* __restrict__ b_ih0,
                                                  const float* __restrict__ b_hh0,
                                                  float* __restrict__ gx0p) {
    __shared__ __align__(16) float xs[32];
    const int t = blockIdx.x;
    const int j = threadIdx.x;
    if (j < 32) xs[j] = x[t * 32 + j];
    __syncthreads();
    const float4* w4 = (const float4*)(w_ih0 + j * 32);
    const float4* x4 = (const float4*)xs;
    float acc = b_ih0[j] + b_hh0[j];
#pragma unroll
    for (int u = 0; u < 8; ++u) {
        float4 w = w4[u];
        float4 xv = x4[u];
        acc += w.x * xv.x + w.y * xv.y + w.z * xv.z + w.w * xv.w;
    }
    const int g = j >> 6;
    const int uu = j & 63;
    gx0p[t * 256 + uu * 4 + g] = acc;
}

// Kernel 2: sequential 2-layer LSTM. 512 threads = 8 waves on 1 CU.
// Waves 0-3 (A): layer0 time i.  Waves 4-7 (B): layer1 time i-1.
// Lane (u = j>>2, q = j&3): all 4 gate rows of unit u over k in [16q,16q+16).
// amdgpu_waves_per_eu(2,2): grid is ONE block (8 waves = 2/EU is the ceiling
// anyway) -> give the allocator the full 256-VGPR budget so the ~200 live
// weight values stay in registers instead of being rematerialized from HBM
// every step (round-3 failure mode: VGPR=88, FETCH_SIZE=2.16 GB).
__global__ __launch_bounds__(512)
__attribute__((amdgpu_waves_per_eu(2, 2))) void lstm_kernel(const float* __restrict__ gx0,
                                                      const float* __restrict__ w_hh0,
                                                      const float* __restrict__ w_ih1,
                                                      const float* __restrict__ w_hh1,
                                                      const float* __restrict__ b_ih1,
                                                      const float* __restrict__ b_hh1,
                                                      float* __restrict__ hc_out) {
    __shared__ __align__(16) float h0buf[2][64];
    __shared__ __align__(16) float h1buf[2][64];

    const int t = threadIdx.x;
    const int j = t & 255;
    const int u = j >> 2;
    const int q = j & 3;
    const int qk = q * 16;
    const bool qg = (q == 2);
    const float kmul = qg ? -2.885390082f : -1.442695041f;
    const float mm = qg ? 2.0f : 1.0f;
    const float dd = qg ? 1.0f : 0.0f;
    const v2f Z2 = {0.0f, 0.0f};
    float cst = 0.0f;

    if (t < 256) {
        // ================= group A: layer 0 =================
        WDECL(wA0_) WDECL(wA1_) WDECL(wA2_) WDECL(wA3_)
        WLOAD(wA0_, w_hh0 + (0 * 64 + u) * 64 + qk)
        WLOAD(wA1_, w_hh0 + (1 * 64 + u) * 64 + qk)
        WLOAD(wA2_, w_hh0 + (2 * 64 + u) * 64 + qk)
        WLOAD(wA3_, w_hh0 + (3 * 64 + u) * 64 + qk)
        const float4* gp = ((const float4*)gx0) + u;
        float4 pf0 = gp[0 * 64];
        float4 pf1 = gp[1 * 64];
        float4 pf2 = gp[2 * 64];
        float4 pf3 = gp[3 * 64];
        if (q == 0) h0buf[1][u] = 0.0f;
        barrier_nd();  // init visible

#define A_STEP(PF, RDP, WRP, ROWI)                                                      \
    {                                                                                   \
        HREAD(h_, &h0buf[RDP][qk])                                                      \
        v2f a0 = Z2, a1 = Z2, a2 = Z2, a3 = Z2;                                         \
        WDOT(a0, wA0_, h_) WDOT(a1, wA1_, h_) WDOT(a2, wA2_, h_) WDOT(a3, wA3_, h_)     \
        float G0 = a0.x + a0.y, G1 = a1.x + a1.y, G2 = a2.x + a2.y, G3 = a3.x + a3.y;   \
        G0 += dppf<0xB1>(G0); G1 += dppf<0xB1>(G1);                                     \
        G2 += dppf<0xB1>(G2); G3 += dppf<0xB1>(G3);                                     \
        G0 += dppf<0x4E>(G0); G1 += dppf<0x4E>(G1);                                     \
        G2 += dppf<0x4E>(G2); G3 += dppf<0x4E>(G3);                                     \
        G0 += PF.x; G1 += PF.y; G2 += PF.z; G3 += PF.w;                                 \
        float arg = q == 0 ? G0 : (q == 1 ? G1 : (q == 2 ? G2 : G3));                   \
        float act = __builtin_fmaf(mm, frcp(1.0f + fexp2(kmul * arg)), -dd);            \
        float gi = dppf<0x00>(act), gf = dppf<0x55>(act);                               \
        float gg = dppf<0xAA>(act), go = dppf<0xFF>(act);                               \
        cst = __builtin_fmaf(gf, cst, gi * gg);                                         \
        float th = __builtin_fmaf(2.0f, frcp(1.0f + fexp2(-2.885390082f * cst)), -1.0f);\
        float hnew = go * th;                                                           \
        if (q == 0) h0buf[WRP][u] = hnew;                                               \
        PF = gp[(ROWI) * 64];                                                           \
        barrier_nd();                                                                   \
    }

        A_STEP(pf0, 1, 0, 4)  // i = 0
#pragma unroll 1
        for (int b = 0; b < 1023; ++b) {  // i = 4b+1 .. 4b+4
            const int i4 = 4 * b;
            A_STEP(pf1, 0, 1, i4 + 5)
            A_STEP(pf2, 1, 0, i4 + 6)
            A_STEP(pf3, 0, 1, i4 + 7)
            A_STEP(pf0, 1, 0, (i4 + 8 < TT ? i4 + 8 : TT - 1))
        }
        A_STEP(pf1, 0, 1, TT - 1)  // i = 4093
        A_STEP(pf2, 1, 0, TT - 1)  // i = 4094
        A_STEP(pf3, 0, 1, TT - 1)  // i = 4095
        barrier_nd();              // i = 4096 (B-only step)
    } else {
        // ================= group B: layer 1 =================
        WDECL(wi0_) WDECL(wi1_) WDECL(wi2_) WDECL(wi3_)
        WDECL(wh0_) WDECL(wh1_) WDECL(wh2_) WDECL(wh3_)
        WLOAD(wi0_, w_ih1 + (0 * 64 + u) * 64 + qk)
        WLOAD(wi1_, w_ih1 + (1 * 64 + u) * 64 + qk)
        WLOAD(wi2_, w_ih1 + (2 * 64 + u) * 64 + qk)
        WLOAD(wi3_, w_ih1 + (3 * 64 + u) * 64 + qk)
        WLOAD(wh0_, w_hh1 + (0 * 64 + u) * 64 + qk)
        WLOAD(wh1_, w_hh1 + (1 * 64 + u) * 64 + qk)
        WLOAD(wh2_, w_hh1 + (2 * 64 + u) * 64 + qk)
        WLOAD(wh3_, w_hh1 + (3 * 64 + u) * 64 + qk)
        float4 bias;
        bias.x = b_ih1[0 * 64 + u] + b_hh1[0 * 64 + u];
        bias.y = b_ih1[1 * 64 + u] + b_hh1[1 * 64 + u];
        bias.z = b_ih1[2 * 64 + u] + b_hh1[2 * 64 + u];
        bias.w = b_ih1[3 * 64 + u] + b_hh1[3 * 64 + u];
        float hlast = 0.0f;
        if (q == 0) h1buf[1][u] = 0.0f;
        barrier_nd();  // pairs with A init barrier
        barrier_nd();  // pairs with A's i=0 step

#define B_STEP(P)                                                                       \
    {                                                                                   \
        HREAD(h_, &h0buf[P][qk])                                                        \
        HREAD(k_, &h1buf[(P) ^ 1][qk])                                                  \
        v2f a0 = Z2, a1 = Z2, a2 = Z2, a3 = Z2;                                         \
        v2f c0 = Z2, c1 = Z2, c2 = Z2, c3 = Z2;                                         \
        WDOT(a0, wi0_, h_) WDOT(a1, wi1_, h_) WDOT(a2, wi2_, h_) WDOT(a3, wi3_, h_)     \
        WDOT(c0, wh0_, k_) WDOT(c1, wh1_, k_) WDOT(c2, wh2_, k_) WDOT(c3, wh3_, k_)     \
        float G0 = (a0.x + a0.y) + (c0.x + c0.y);                                       \
        float G1 = (a1.x + a1.y) + (c1.x + c1.y);                                       \
        float G2 = (a2.x + a2.y) + (c2.x + c2.y);                                       \
        float G3 = (a3.x + a3.y) + (c3.x + c3.y);                                       \
        G0 += dppf<0xB1>(G0); G1 += dppf<0xB1>(G1);                                     \
        G2 += dppf<0xB1>(G2); G3 += dppf<0xB1>(G3);                                     \
        G0 += dppf<0x4E>(G0); G1 += dppf<0x4E>(G1);                                     \
        G2 += dppf<0x4E>(G2); G3 += dppf<0x4E>(G3);                                     \
        G0 += bias.x; G1 += bias.y; G2 += bias.z; G3 += bias.w;                         \
        float arg = q == 0 ? G0 : (q == 1 ? G1 : (q == 2 ? G2 : G3));                   \
        float act = __builtin_fmaf(mm, frcp(1.0f + fexp2(kmul * arg)), -dd);            \
        float gi = dppf<0x00>(act), gf = dppf<0x55>(act);                               \
        float gg = dppf<0xAA>(act), go = dppf<0xFF>(act);                               \
        cst = __builtin_fmaf(gf, cst, gi * gg);                                         \
        float th = __builtin_fmaf(2.0f, frcp(1.0f + fexp2(-2.885390082f * cst)), -1.0f);\
        float hnew = go * th;                                                           \
        hlast = hnew;                                                                   \
        if (q == 0) h1buf[P][u] = hnew;                                                 \
        barrier_nd();                                                                   \
    }

#pragma unroll 1
        for (int b = 0; b < 1023; ++b) {
            B_STEP(0)
            B_STEP(1)
            B_STEP(0)
            B_STEP(1)
        }
        B_STEP(0)  // i = 4093
        B_STEP(1)  // i = 4094
        B_STEP(0)  // i = 4095
        B_STEP(1)  // i = 4096 -> h1_4095 (final)
        if (q == 0) {
            hc_out[u] = hlast;
            hc_out[64 + u] = cst;
        }
    }
}

// Kernel 3: out[0..800000) = c1 @ w_es.T + b_es ; out[800000..1.6M) = h1 @ w_eh.T + b_eh
__global__ __launch_bounds__(256) void proj_kernel(const float* __restrict__ hc,
                                                   const float* __restrict__ w_es,
                                                   const float* __restrict__ b_es,
                                                   const float* __restrict__ w_eh,
                                                   const float* __restrict__ b_eh,
                                                   float* __restrict__ out) {
    __shared__ __align__(16) float hv[64];
    __shared__ __align__(16) float cv[64];
    const int tid = threadIdx.x;
    if (tid < 64) hv[tid] = hc[tid];
    else if (tid < 128) cv[tid - 64] = hc[tid];
    __syncthreads();

    const int p = tid & 3;
    const long r = (long)blockIdx.x * 64 + (tid >> 2);
    const float* w;
    const float* bb;
    const float* v;
    long rr;
    if (r < DPROJ) {
        rr = r;
        w = w_es;
        bb = b_es;
        v = cv;
    } else {
        rr = r - DPROJ;
        w = w_eh;
        bb = b_eh;
        v = hv;
    }
    const float4* wp = (const float4*)(w + rr * 64 + p * 16);
    const float4* vp = (const float4*)(v + p * 16);
    v2f s = {0.0f, 0.0f};
#pragma unroll
    for (int cc = 0; cc < 4; ++cc) {
        float4 wv = wp[cc];
        float4 vv = vp[cc];
        v2f w01 = {wv.x, wv.y}, v01 = {vv.x, vv.y};
        v2f w23 = {wv.z, wv.w}, v23 = {vv.z, vv.w};
        s = pkfma(w01, v01, s);
        s = pkfma(w23, v23, s);
    }
    float sum = s.x + s.y;
    sum += dppf<0xB1>(sum);
    sum += dppf<0x4E>(sum);
    if (p == 0) out[r] = sum + bb[rr];
}

extern "C" void kernel_launch(void* const* d_in, const int* in_sizes, int n_in,
                              void* d_out, int out_size, void* d_ws, size_t ws_size,
                              hipStream_t stream) {
    const float* x = (const float*)d_in[0];
    const float* w_ih0 = (const float*)d_in[1];
    const float* w_hh0 = (const float*)d_in[2];
    const float* b_ih0 = (const float*)d_in[3];
    const float* b_hh0 = (const float*)d_in[4];
    const float* w_ih1 = (const float*)d_in[5];
    const float* w_hh1 = (const float*)d_in[6];
    const float* b_ih1 = (const float*)d_in[7];
    const float* b_hh1 = (const float*)d_in[8];
    const float* w_eh = (const float*)d_in[9];
    const float* b_eh = (const float*)d_in[10];
    const float* w_es = (const float*)d_in[11];
    const float* b_es = (const float*)d_in[12];
    float* out = (float*)d_out;

    float* gx0 = (float*)d_ws;     // 4096*256 floats = 4 MB (permuted float4-per-unit)
    float* hc = gx0 + 4096 * 256;  // 128 floats: [h1(64), c1(64)]

    gx0_kernel<<<4096, 256, 0, stream>>>(x, w_ih0, b_ih0, b_hh0, gx0);
    lstm_kernel<<<1, 512, 0, stream>>>(gx0, w_hh0, w_ih1, w_hh1, b_ih1, b_hh1, hc);
    proj_kernel<<<2 * DPROJ / 64, 256, 0, stream>>>(hc, w_es, b_es, w_eh, b_eh, out);
}